// Round 2
// baseline (25394.139 us; speedup 1.0000x reference)
//
#include <hip/hip_runtime.h>

// GRUPlant persistent-kernel rewrite.
// B=256, T_IN=512, T_TGT=256, N_IN=64, N_PV=16, H=256, EMB=32.
// Batch rows are independent chains -> 16 blocks x 16 rows, one persistent
// kernel, no inter-block sync. State (h0,h1,pv) lives in LDS across all steps.
// Compute: v_mfma_f32_16x16x32_f16, fp32 accumulate, fp32 h master in LDS.
// Weights pre-swizzled to MFMA B-fragment layout: chunk(kt,gt) = 64 lanes x 16B,
// lane l holds W[g = gt*16 + (l&15)][k = kt*32 + (l>>4)*8 + j], j=0..7.

typedef _Float16 f16x8 __attribute__((ext_vector_type(8)));
typedef float f32x4 __attribute__((ext_vector_type(4)));

#define XSTR 104   // 96 + 8 pad (f16)
#define HSTR 264   // 256 + 8 pad (f16)
#define H32S 260   // 256 + 4 pad (f32)
#define YSTR 136   // 128 + 8 pad (f16)

// ws layout offsets in f16 elements (each chunk = 512 f16 = 1KB)
#define OFF_E0IH 0u          // 3*48 chunks (K=96)
#define OFF_E0HH 73728u      // 8*48
#define OFF_E1IH 270336u     // 8*48
#define OFF_E1HH 466944u     // 8*48
#define OFF_D0IH 663552u     // 3*48 (K=80 padded to 96)
#define OFF_D0HH 737280u     // 8*48
#define OFF_D1IH 933888u     // 8*48
#define OFF_D1HH 1130496u    // 8*48
#define OFF_FC1  1327104u    // 8*8
#define OFF_FC2  1359872u    // 4*1
#define W_TOTAL_F16 1361920u
#define BIAS_BYTE_OFF (W_TOTAL_F16 * 2u)   // 2723840, 4-aligned

__device__ __forceinline__ float sigm(float x) { return 1.f / (1.f + __expf(-x)); }
__device__ __forceinline__ float tanh_fast(float x) { return 1.f - 2.f / (__expf(2.f * x) + 1.f); }

// ---- prep: swizzle a (rows x K_src) fp32 weight into B-fragment chunks ----
__global__ __launch_bounds__(256) void prep_w(const float* __restrict__ W,
                                              _Float16* __restrict__ dst,
                                              int K_src, int GT, int total_threads) {
    int idx = blockIdx.x * 256 + threadIdx.x;
    if (idx >= total_threads) return;
    int l = idx & 63, c = idx >> 6;
    int kt = c / GT, gt = c - kt * GT;
    int g = gt * 16 + (l & 15);
    int k0 = kt * 32 + (l >> 4) * 8;
    _Float16 tmp[8];
#pragma unroll
    for (int j = 0; j < 8; ++j) {
        int k = k0 + j;
        tmp[j] = (k < K_src) ? (_Float16)W[(size_t)g * K_src + k] : (_Float16)0.f;
    }
    *(f16x8*)(dst + (size_t)c * 512 + (size_t)l * 8) = *(f16x8*)tmp;
}

// ---- prep: combine biases into [bR(256)|bZ(256)|bNi(256)|bNh(256)] ----
__global__ __launch_bounds__(256) void prep_bias(const float* __restrict__ bih,
                                                 const float* __restrict__ bhh,
                                                 float* __restrict__ dst) {
    int i = threadIdx.x;
    dst[i]       = bih[i]       + bhh[i];
    dst[256 + i] = bih[256 + i] + bhh[256 + i];
    dst[512 + i] = bih[512 + i];
    dst[768 + i] = bhh[512 + i];
}

// One GRU layer step for 16 rows. X = layer input (x-part), HF = this layer's
// f16 h-state (also h-part A source), H32 = fp32 h master. KTX = x-part k-tiles.
template <int KTX>
__device__ __forceinline__ void gru_layer(
    const _Float16* __restrict__ X, int xstr,
    _Float16* __restrict__ HF, float* __restrict__ H32,
    const _Float16* __restrict__ Bih, const _Float16* __restrict__ Bhh,
    const float* __restrict__ bias)
{
    const int tid = threadIdx.x;
    const int l = tid & 63, w = tid >> 6;
    const int ht0 = w, ht1 = w + 8;          // this wave's two h-col tiles
    const int arow = l & 15, aq = (l >> 4) * 8;

    f32x4 aR0 = {0.f,0.f,0.f,0.f}, aZ0 = aR0, aNi0 = aR0, aNh0 = aR0;
    f32x4 aR1 = aR0, aZ1 = aR0, aNi1 = aR0, aNh1 = aR0;

    const f16x8* Bi = ((const f16x8*)Bih) + l;
    const f16x8* Bh = ((const f16x8*)Bhh) + l;
    const _Float16* Xp = X + arow * xstr + aq;
    const _Float16* Hp = HF + arow * HSTR + aq;

#pragma unroll
    for (int kt = 0; kt < KTX; ++kt) {
        f16x8 a = *(const f16x8*)(Xp + kt * 32);
        int c = kt * 48;
        aR0  = __builtin_amdgcn_mfma_f32_16x16x32_f16(a, Bi[(size_t)(c + ht0) * 64],      aR0, 0, 0, 0);
        aZ0  = __builtin_amdgcn_mfma_f32_16x16x32_f16(a, Bi[(size_t)(c + 16 + ht0) * 64], aZ0, 0, 0, 0);
        aNi0 = __builtin_amdgcn_mfma_f32_16x16x32_f16(a, Bi[(size_t)(c + 32 + ht0) * 64], aNi0, 0, 0, 0);
        aR1  = __builtin_amdgcn_mfma_f32_16x16x32_f16(a, Bi[(size_t)(c + ht1) * 64],      aR1, 0, 0, 0);
        aZ1  = __builtin_amdgcn_mfma_f32_16x16x32_f16(a, Bi[(size_t)(c + 16 + ht1) * 64], aZ1, 0, 0, 0);
        aNi1 = __builtin_amdgcn_mfma_f32_16x16x32_f16(a, Bi[(size_t)(c + 32 + ht1) * 64], aNi1, 0, 0, 0);
    }
#pragma unroll
    for (int kt = 0; kt < 8; ++kt) {
        f16x8 a = *(const f16x8*)(Hp + kt * 32);
        int c = kt * 48;
        aR0  = __builtin_amdgcn_mfma_f32_16x16x32_f16(a, Bh[(size_t)(c + ht0) * 64],      aR0, 0, 0, 0);
        aZ0  = __builtin_amdgcn_mfma_f32_16x16x32_f16(a, Bh[(size_t)(c + 16 + ht0) * 64], aZ0, 0, 0, 0);
        aNh0 = __builtin_amdgcn_mfma_f32_16x16x32_f16(a, Bh[(size_t)(c + 32 + ht0) * 64], aNh0, 0, 0, 0);
        aR1  = __builtin_amdgcn_mfma_f32_16x16x32_f16(a, Bh[(size_t)(c + ht1) * 64],      aR1, 0, 0, 0);
        aZ1  = __builtin_amdgcn_mfma_f32_16x16x32_f16(a, Bh[(size_t)(c + 16 + ht1) * 64], aZ1, 0, 0, 0);
        aNh1 = __builtin_amdgcn_mfma_f32_16x16x32_f16(a, Bh[(size_t)(c + 32 + ht1) * 64], aNh1, 0, 0, 0);
    }

    __syncthreads();   // all A-reads of HF done before we overwrite it

#pragma unroll
    for (int p = 0; p < 2; ++p) {
        int ht = p ? ht1 : ht0;
        f32x4 aR = p ? aR1 : aR0, aZ = p ? aZ1 : aZ0;
        f32x4 aNi = p ? aNi1 : aNi0, aNh = p ? aNh1 : aNh0;
        int hc = ht * 16 + (l & 15);
        float bR = bias[hc], bZ = bias[256 + hc], bNi = bias[512 + hc], bNh = bias[768 + hc];
#pragma unroll
        for (int i = 0; i < 4; ++i) {
            int row = (l >> 4) * 4 + i;   // C/D layout: col=lane&15, row=quad*4+reg
            float r = sigm(aR[i] + bR);
            float z = sigm(aZ[i] + bZ);
            float n = tanh_fast(aNi[i] + bNi + r * (aNh[i] + bNh));
            float hp = H32[row * H32S + hc];
            float hn = (1.f - z) * n + z * hp;
            H32[row * H32S + hc] = hn;
            HF[row * HSTR + hc] = (_Float16)hn;
        }
    }
    __syncthreads();
}

__global__ __launch_bounds__(512) void plant(
    const float* __restrict__ x_cv, const float* __restrict__ x_tgt,
    const float* __restrict__ pv_init, const int* __restrict__ scen,
    const float* __restrict__ emb,
    const _Float16* __restrict__ W, const float* __restrict__ bias,
    const float* __restrict__ fc1b, const float* __restrict__ fc2b,
    float* __restrict__ out)
{
    __shared__ _Float16 XF[16 * XSTR];
    __shared__ _Float16 H0F[16 * HSTR];
    __shared__ _Float16 H1F[16 * HSTR];
    __shared__ _Float16 YF[16 * YSTR];
    __shared__ float H0_32[16 * H32S];
    __shared__ float H1_32[16 * H32S];

    const int tid = threadIdx.x;
    const int l = tid & 63, w = tid >> 6;
    const int r0 = blockIdx.x * 16;

    // ---- init: zero h state, stage scenario embedding into XF[.][64..95] ----
    for (int i = tid; i < 16 * HSTR; i += 512) { H0F[i] = (_Float16)0.f; H1F[i] = (_Float16)0.f; }
    for (int i = tid; i < 16 * H32S; i += 512) { H0_32[i] = 0.f; H1_32[i] = 0.f; }
    {
        int row = tid >> 5, e = tid & 31;   // 512 threads == 16*32 elems
        XF[row * XSTR + 64 + e] = (_Float16)emb[scen[r0 + row] * 32 + e];
    }
    __syncthreads();

    const int row_s = tid >> 5, c_s = (tid & 31) * 2;  // staging coords (2 cols/thread)

    // ================= encoder =================
    {
        const float* xp = x_cv + (size_t)(r0 + row_s) * (512 * 64) + c_s;
        float2 xn = *(const float2*)xp;   // t=0 prefetch
        for (int t = 0; t < 512; ++t) {
            XF[row_s * XSTR + c_s]     = (_Float16)xn.x;
            XF[row_s * XSTR + c_s + 1] = (_Float16)xn.y;
            __syncthreads();
            if (t + 1 < 512) xn = *(const float2*)(xp + (size_t)(t + 1) * 64);
            gru_layer<3>(XF, XSTR, H0F, H0_32, W + OFF_E0IH, W + OFF_E0HH, bias);
            gru_layer<8>(H0F, HSTR, H1F, H1_32, W + OFF_E1IH, W + OFF_E1HH, bias + 1024);
        }
    }

    // ---- decoder pv slot init: XF[.][64..79] = pv_init, [80..95] = 0 ----
    {
        int row = tid >> 5, cc = tid & 31;
        XF[row * XSTR + 64 + cc] = (cc < 16) ? (_Float16)pv_init[(r0 + row) * 16 + cc]
                                             : (_Float16)0.f;
    }
    __syncthreads();

    // ================= decoder =================
    {
        const float* xp = x_tgt + (size_t)(r0 + row_s) * (256 * 64) + c_s;
        float2 xn = *(const float2*)xp;
        for (int s = 0; s < 256; ++s) {
            XF[row_s * XSTR + c_s]     = (_Float16)xn.x;
            XF[row_s * XSTR + c_s + 1] = (_Float16)xn.y;
            __syncthreads();
            if (s + 1 < 256) xn = *(const float2*)(xp + (size_t)(s + 1) * 64);
            gru_layer<3>(XF, XSTR, H0F, H0_32, W + OFF_D0IH, W + OFF_D0HH, bias + 2048);
            gru_layer<8>(H0F, HSTR, H1F, H1_32, W + OFF_D1IH, W + OFF_D1HH, bias + 3072);

            // ---- fc1: wave w -> out tile w (16 of 128), K=256 from H1F ----
            {
                f32x4 acc = {0.f,0.f,0.f,0.f};
                const f16x8* Bf = ((const f16x8*)(W + OFF_FC1)) + l;
                const _Float16* Hp = H1F + (l & 15) * HSTR + ((l >> 4) * 8);
#pragma unroll
                for (int kt = 0; kt < 8; ++kt) {
                    f16x8 a = *(const f16x8*)(Hp + kt * 32);
                    acc = __builtin_amdgcn_mfma_f32_16x16x32_f16(a, Bf[(size_t)(kt * 8 + w) * 64], acc, 0, 0, 0);
                }
                int f = w * 16 + (l & 15);
                float bb = fc1b[f];
#pragma unroll
                for (int i = 0; i < 4; ++i) {
                    int row = (l >> 4) * 4 + i;
                    YF[row * YSTR + f] = (_Float16)fmaxf(acc[i] + bb, 0.f);
                }
            }
            __syncthreads();

            // ---- fc2 (wave 0 only): 16 outs, K=128 from YF ----
            if (w == 0) {
                f32x4 acc = {0.f,0.f,0.f,0.f};
                const f16x8* Bf = ((const f16x8*)(W + OFF_FC2)) + l;
                const _Float16* Yp = YF + (l & 15) * YSTR + ((l >> 4) * 8);
#pragma unroll
                for (int kt = 0; kt < 4; ++kt) {
                    f16x8 a = *(const f16x8*)(Yp + kt * 32);
                    acc = __builtin_amdgcn_mfma_f32_16x16x32_f16(a, Bf[(size_t)kt * 64], acc, 0, 0, 0);
                }
                int col = l & 15;
                float bb = fc2b[col];
#pragma unroll
                for (int i = 0; i < 4; ++i) {
                    int row = (l >> 4) * 4 + i;
                    float y = acc[i] + bb;
                    out[(size_t)(r0 + row) * 4096 + (size_t)s * 16 + col] = y;
                    XF[row * XSTR + 64 + col] = (_Float16)y;   // pv feedback
                }
            }
            __syncthreads();
        }
    }
}

extern "C" void kernel_launch(void* const* d_in, const int* in_sizes, int n_in,
                              void* d_out, int out_size, void* d_ws, size_t ws_size,
                              hipStream_t stream)
{
    const float* x_cv    = (const float*)d_in[0];
    const float* x_tgt   = (const float*)d_in[1];
    const float* pv_init = (const float*)d_in[2];
    const int*   scen    = (const int*)d_in[3];
    const float* emb     = (const float*)d_in[4];
    const float* eWih0 = (const float*)d_in[5];
    const float* eWhh0 = (const float*)d_in[6];
    const float* ebih0 = (const float*)d_in[7];
    const float* ebhh0 = (const float*)d_in[8];
    const float* eWih1 = (const float*)d_in[9];
    const float* eWhh1 = (const float*)d_in[10];
    const float* ebih1 = (const float*)d_in[11];
    const float* ebhh1 = (const float*)d_in[12];
    const float* dWih0 = (const float*)d_in[13];
    const float* dWhh0 = (const float*)d_in[14];
    const float* dbih0 = (const float*)d_in[15];
    const float* dbhh0 = (const float*)d_in[16];
    const float* dWih1 = (const float*)d_in[17];
    const float* dWhh1 = (const float*)d_in[18];
    const float* dbih1 = (const float*)d_in[19];
    const float* dbhh1 = (const float*)d_in[20];
    const float* fc1W = (const float*)d_in[21];
    const float* fc1b = (const float*)d_in[22];
    const float* fc2W = (const float*)d_in[23];
    const float* fc2b = (const float*)d_in[24];
    float* out = (float*)d_out;

    _Float16* W = (_Float16*)d_ws;
    float* bias = (float*)((char*)d_ws + BIAS_BYTE_OFF);

    auto lp = [&](const float* src, unsigned off, int K_src, int KT, int GT) {
        int total = KT * GT * 64;
        prep_w<<<(total + 255) / 256, 256, 0, stream>>>(src, W + off, K_src, GT, total);
    };
    lp(eWih0, OFF_E0IH, 96, 3, 48);
    lp(eWhh0, OFF_E0HH, 256, 8, 48);
    lp(eWih1, OFF_E1IH, 256, 8, 48);
    lp(eWhh1, OFF_E1HH, 256, 8, 48);
    lp(dWih0, OFF_D0IH, 80, 3, 48);    // K 80 zero-padded to 96
    lp(dWhh0, OFF_D0HH, 256, 8, 48);
    lp(dWih1, OFF_D1IH, 256, 8, 48);
    lp(dWhh1, OFF_D1HH, 256, 8, 48);
    lp(fc1W, OFF_FC1, 256, 8, 8);
    lp(fc2W, OFF_FC2, 128, 4, 1);
    prep_bias<<<1, 256, 0, stream>>>(ebih0, ebhh0, bias);
    prep_bias<<<1, 256, 0, stream>>>(ebih1, ebhh1, bias + 1024);
    prep_bias<<<1, 256, 0, stream>>>(dbih0, dbhh0, bias + 2048);
    prep_bias<<<1, 256, 0, stream>>>(dbih1, dbhh1, bias + 3072);

    plant<<<16, 512, 0, stream>>>(x_cv, x_tgt, pv_init, scen, emb,
                                  W, bias, fc1b, fc2b, out);
}

// Round 3
// 14420.430 us; speedup vs baseline: 1.7610x; 1.7610x over previous
//
#include <hip/hip_runtime.h>

// GRUPlant tensor-parallel persistent kernel.
// B=256, T_IN=512, T_TGT=256, N_IN=64, N_PV=16, H=256, EMB=32.
// 256 blocks x 384 threads (6 waves). Block (g,cg): batch rows [16g,16g+16),
// hidden cols [16cg,16cg+16). Gate weights live in VGPRs as MFMA B-fragments.
// Per step, blocks of a group exchange 16x16 h-slices through global memory
// with agent-scope release/acquire (ticket flags). Groups are independent.

typedef _Float16 f16x8 __attribute__((ext_vector_type(8)));
typedef float f32x4 __attribute__((ext_vector_type(4)));

// ---- pre-swizzled weight layout in d_ws (f16 elems; chunk = 512 f16 = 1KB) ----
#define OFF_E0IH 0u          // 3kt x 48gt
#define OFF_E0HH 73728u      // 8 x 48
#define OFF_E1IH 270336u
#define OFF_E1HH 466944u
#define OFF_D0IH 663552u     // K=80 zero-padded to 96
#define OFF_D0HH 737280u
#define OFF_D1IH 933888u
#define OFF_D1HH 1130496u
#define OFF_FC1  1327104u    // 8kt x 8gt
#define OFF_FC2  1359872u    // 4kt x 1gt
#define W_TOTAL_F16 1361920u
#define BIAS_BYTE_OFF 2723840u   // 4 layers x 1024 f32
#define EXCH_BYTE_OFF 2740224u
// ---- exchange region (bytes, relative to EXCH_BYTE_OFF) ----
#define EX_H0 0          // [2][256][256] f16
#define EX_H1 262144     // [2][256][256] f16
#define EX_F1 524288     // [256][128] f16
#define EX_PV 589824     // [256][16] f16
#define EX_FLAGS 598016  // [16][16] int
#define EX_BYTES 599040

__device__ __forceinline__ float sigm(float x) { return 1.f / (1.f + __expf(-x)); }
__device__ __forceinline__ float tanh_fast(float x) { return 1.f - 2.f / (__expf(2.f * x) + 1.f); }

// ---- prep: swizzle (rows x K_src) fp32 weight into MFMA-B fragment chunks ----
// chunk c = kt*GT+gt; lane l holds W[g=gt*16+(l&15)][k=kt*32+(l>>4)*8+j], j=0..7
__global__ __launch_bounds__(256) void prep_w(const float* __restrict__ W,
                                              _Float16* __restrict__ dst,
                                              int K_src, int GT, int total_threads) {
    int idx = blockIdx.x * 256 + threadIdx.x;
    if (idx >= total_threads) return;
    int l = idx & 63, c = idx >> 6;
    int kt = c / GT, gt = c - kt * GT;
    int g = gt * 16 + (l & 15);
    int k0 = kt * 32 + (l >> 4) * 8;
    _Float16 tmp[8];
#pragma unroll
    for (int j = 0; j < 8; ++j) {
        int k = k0 + j;
        tmp[j] = (k < K_src) ? (_Float16)W[(size_t)g * K_src + k] : (_Float16)0.f;
    }
    *(f16x8*)(dst + (size_t)c * 512 + (size_t)l * 8) = *(f16x8*)tmp;
}

// ---- prep: combine biases into [bR|bZ|bNi|bNh] x 256 ----
__global__ __launch_bounds__(256) void prep_bias(const float* __restrict__ bih,
                                                 const float* __restrict__ bhh,
                                                 float* __restrict__ dst) {
    int i = threadIdx.x;
    dst[i]       = bih[i]       + bhh[i];
    dst[256 + i] = bih[256 + i] + bhh[256 + i];
    dst[512 + i] = bih[512 + i];
    dst[768 + i] = bhh[512 + i];
}

template <int KT>
__device__ __forceinline__ f32x4 mmk(const _Float16* ap, const f16x8 (&B)[8]) {
    f32x4 acc = {0.f, 0.f, 0.f, 0.f};
#pragma unroll
    for (int kt = 0; kt < KT; ++kt)
        acc = __builtin_amdgcn_mfma_f32_16x16x32_f16(*(const f16x8*)(ap + (size_t)kt * 32),
                                                     B[kt], acc, 0, 0, 0);
    return acc;
}

// GRU nonlinearity + state update for one 16x16 tile (one wave, 4 elems/lane).
__device__ __forceinline__ void h_update(const float* Gb, float* HM,
                                         _Float16* hex_slice, int l,
                                         float bR, float bZ, float bNi, float bNh) {
#pragma unroll
    for (int i = 0; i < 4; ++i) {
        int row = (l >> 4) * 4 + i, col = l & 15;
        int rc = row * 17 + col;
        float r = sigm(Gb[rc] + bR);
        float z = sigm(Gb[272 + rc] + bZ);
        float n = tanh_fast(Gb[2 * 272 + rc] + bNi + r * (Gb[3 * 272 + rc] + bNh));
        float hp = HM[row * 16 + col];
        float hn = (1.f - z) * n + z * hp;
        HM[row * 16 + col] = hn;
        hex_slice[(size_t)row * 256 + col] = (_Float16)hn;
    }
}

__global__ __launch_bounds__(384, 2) void plant(
    const float* __restrict__ x_cv, const float* __restrict__ x_tgt,
    const float* __restrict__ pv_init, const int* __restrict__ scen,
    const float* __restrict__ emb,
    const _Float16* __restrict__ Wsw, const float* __restrict__ bias4,
    const float* __restrict__ fc1b, const float* __restrict__ fc2b,
    char* __restrict__ exch, float* __restrict__ out)
{
    __shared__ _Float16 XF[16 * 104];       // [x(64)|emb-or-pv(32)] f16, pad 8
    __shared__ float G[2][4][272];          // gate tiles [layer][R,Z,Ni,Nh][16x17]
    __shared__ float H0M[256], H1M[256];    // fp32 h masters (own 16x16 slice)
    __shared__ _Float16 FC1S[8 * 512];      // fc1 B-frag slice (even cg)
    __shared__ _Float16 FC2S[4 * 512];      // fc2 B-frags (cg 0)

    const int tid = threadIdx.x;
    const int l = tid & 63, w = tid >> 6;
    const int g = blockIdx.x >> 4, cg = blockIdx.x & 15;
    const int g16 = g * 16;
    const int j = (w < 3) ? w : w - 3;      // gate role: 0=r,1=z,2=n
    const int gt = j * 16 + cg;

    _Float16* h0ex = (_Float16*)(exch + EX_H0);
    _Float16* h1ex = (_Float16*)(exch + EX_H1);
    _Float16* f1ex = (_Float16*)(exch + EX_F1);
    _Float16* pvex = (_Float16*)(exch + EX_PV);
    int* gflags = (int*)(exch + EX_FLAGS) + g * 16;

    const int arow = l & 15, acol8 = (l >> 4) * 8;
    const size_t hoff = (size_t)(g16 + arow) * 256 + acol8;        // + kt*32
    const size_t slice_off = (size_t)g16 * 256 + cg * 16;
    const _Float16* XFp = XF + arow * 104 + acol8;

    int ticket = 0;
    auto barrier = [&](int target) {
        __syncthreads();   // drain all waves' stores (compiler emits vmcnt(0))
        if (w == 0) {
            if (l == 0)
                __hip_atomic_fetch_add(&gflags[cg], 1, __ATOMIC_RELEASE,
                                       __HIP_MEMORY_SCOPE_AGENT);
            if (l < 16) {
                while (__hip_atomic_fetch_add(&gflags[l], 0, __ATOMIC_RELAXED,
                                              __HIP_MEMORY_SCOPE_AGENT) < target)
                    __builtin_amdgcn_s_sleep(1);
            }
            __builtin_amdgcn_fence(__ATOMIC_ACQUIRE, "agent");  // inv L1/L2
        }
        __syncthreads();
    };

    // ---- init ----
    for (int i = tid; i < 256; i += 384) { H0M[i] = 0.f; H1M[i] = 0.f; }
    if (tid < 256) {                        // scenario embedding -> XF[64..95]
        int row = tid >> 4, c2 = (tid & 15) * 2;
        int sc = scen[g16 + row];
        XF[row * 104 + 64 + c2]     = (_Float16)emb[sc * 32 + c2];
        XF[row * 104 + 64 + c2 + 1] = (_Float16)emb[sc * 32 + c2 + 1];
    }

    // gate weights -> registers (encoder)
    f16x8 Bx[8], Bh[8];
    {
        unsigned offi = (w < 3) ? OFF_E0IH : OFF_E1IH;
        unsigned offh = (w < 3) ? OFF_E0HH : OFF_E1HH;
        int ktx = (w < 3) ? 3 : 8;
#pragma unroll
        for (int kt = 0; kt < 8; ++kt) {
            if (kt < ktx) Bx[kt] = *(const f16x8*)(Wsw + offi + (size_t)(kt * 48 + gt) * 512 + l * 8);
            Bh[kt] = *(const f16x8*)(Wsw + offh + (size_t)(kt * 48 + gt) * 512 + l * 8);
        }
    }
    float bR = 0.f, bZ = 0.f, bNi = 0.f, bNh = 0.f;
    {
        const float* bb = (w == 0) ? bias4 : bias4 + 1024;
        int hc = cg * 16 + (l & 15);
        if (w == 0 || w == 3) { bR = bb[hc]; bZ = bb[256 + hc]; bNi = bb[512 + hc]; bNh = bb[768 + hc]; }
    }

    // x prefetch (threads 0..255 hold one float4 = 4 input cols of one row)
    float4 xpre;
    const float* xsrc0 = x_cv + (size_t)(g16 + (tid >> 4)) * (512 * 64) + (tid & 15) * 4;
    if (tid < 256) xpre = *(const float4*)xsrc0;
    __syncthreads();

    // ================= encoder: t = 0..512 (layer1 lags by 1) =================
    for (int t = 0; t <= 512; ++t) {
        if (t < 512 && tid < 256) {
            int row = tid >> 4, c4 = (tid & 15) * 4;
            XF[row * 104 + c4]     = (_Float16)xpre.x;
            XF[row * 104 + c4 + 1] = (_Float16)xpre.y;
            XF[row * 104 + c4 + 2] = (_Float16)xpre.z;
            XF[row * 104 + c4 + 3] = (_Float16)xpre.w;
        }
        __syncthreads();
        if (tid < 256 && t + 1 < 512) xpre = *(const float4*)(xsrc0 + (size_t)(t + 1) * 64);

        bool doL0 = (w < 3) && (t < 512);
        bool doL1 = (w >= 3) && (t > 0);
        f32x4 accX = {0.f,0.f,0.f,0.f}, accH = accX;
        if (doL0) {
            accX = mmk<3>(XFp, Bx);
            accH = mmk<8>(h0ex + (size_t)((t - 1) & 1) * 65536 + hoff, Bh);
        } else if (doL1) {
            accX = mmk<8>(h0ex + (size_t)((t - 1) & 1) * 65536 + hoff, Bx);   // h0(t-1)
            accH = mmk<8>(h1ex + (size_t)(t & 1) * 65536 + hoff, Bh);         // h1(t-2)
        }
        if (doL0 || doL1) {
            float* Gb = &G[(w < 3) ? 0 : 1][0][0];
#pragma unroll
            for (int i = 0; i < 4; ++i) {
                int rc = ((l >> 4) * 4 + i) * 17 + (l & 15);
                if (j < 2) Gb[j * 272 + rc] = accX[i] + accH[i];
                else { Gb[2 * 272 + rc] = accX[i]; Gb[3 * 272 + rc] = accH[i]; }
            }
        }
        __syncthreads();
        if (w == 0 && t < 512)
            h_update(&G[0][0][0], H0M, h0ex + (size_t)(t & 1) * 65536 + slice_off, l, bR, bZ, bNi, bNh);
        if (w == 3 && t > 0)
            h_update(&G[1][0][0], H1M, h1ex + (size_t)((t - 1) & 1) * 65536 + slice_off, l, bR, bZ, bNi, bNh);
        barrier(++ticket);
    }

    // ================= phase switch: decoder weights =================
    {
        unsigned offi = (w < 3) ? OFF_D0IH : OFF_D1IH;
        unsigned offh = (w < 3) ? OFF_D0HH : OFF_D1HH;
        int ktx = (w < 3) ? 3 : 8;
#pragma unroll
        for (int kt = 0; kt < 8; ++kt) {
            if (kt < ktx) Bx[kt] = *(const f16x8*)(Wsw + offi + (size_t)(kt * 48 + gt) * 512 + l * 8);
            Bh[kt] = *(const f16x8*)(Wsw + offh + (size_t)(kt * 48 + gt) * 512 + l * 8);
        }
        const float* bb = (w == 0) ? bias4 + 2048 : bias4 + 3072;
        int hc = cg * 16 + (l & 15);
        if (w == 0 || w == 3) { bR = bb[hc]; bZ = bb[256 + hc]; bNi = bb[512 + hc]; bNh = bb[768 + hc]; }
    }
    if (!(cg & 1))
        for (int i = tid; i < 4096; i += 384)
            FC1S[i] = Wsw[OFF_FC1 + (size_t)((i >> 9) * 8 + (cg >> 1)) * 512 + (i & 511)];
    if (cg == 0)
        for (int i = tid; i < 2048; i += 384)
            FC2S[i] = Wsw[OFF_FC2 + i];
    float f1breg = fc1b[16 * (cg >> 1) + (l & 15)];
    float f2breg = fc2b[l & 15];
    const float* xsrc1 = x_tgt + (size_t)(g16 + (tid >> 4)) * (256 * 64) + (tid & 15) * 4;
    if (tid < 256) xpre = *(const float4*)xsrc1;
    __syncthreads();

    // ================= decoder: s = 0..255, 4 sub-barriers/step =================
    for (int s = 0; s < 256; ++s) {
        // ---- stage XF: x_tgt(s) + pv feedback ----
        if (tid < 256) {
            int row = tid >> 4, c4 = (tid & 15) * 4, col = tid & 15;
            XF[row * 104 + c4]     = (_Float16)xpre.x;
            XF[row * 104 + c4 + 1] = (_Float16)xpre.y;
            XF[row * 104 + c4 + 2] = (_Float16)xpre.z;
            XF[row * 104 + c4 + 3] = (_Float16)xpre.w;
            XF[row * 104 + 64 + col] = (s == 0) ? (_Float16)pv_init[(g16 + row) * 16 + col]
                                                : pvex[(g16 + row) * 16 + col];
            // cols 80..95 hold stale emb; their weights are zero-padded -> harmless
        }
        __syncthreads();
        if (tid < 256 && s + 1 < 256) xpre = *(const float4*)(xsrc1 + (size_t)(s + 1) * 64);

        // ---- stage A: d0 gates ----
        if (w < 3) {
            f32x4 accX = mmk<3>(XFp, Bx);
            f32x4 accH = mmk<8>(h0ex + (size_t)((s - 1) & 1) * 65536 + hoff, Bh);
            float* Gb = &G[0][0][0];
#pragma unroll
            for (int i = 0; i < 4; ++i) {
                int rc = ((l >> 4) * 4 + i) * 17 + (l & 15);
                if (j < 2) Gb[j * 272 + rc] = accX[i] + accH[i];
                else { Gb[2 * 272 + rc] = accX[i]; Gb[3 * 272 + rc] = accH[i]; }
            }
        }
        __syncthreads();
        if (w == 0)
            h_update(&G[0][0][0], H0M, h0ex + (size_t)(s & 1) * 65536 + slice_off, l, bR, bZ, bNi, bNh);
        barrier(++ticket);

        // ---- stage B: d1 gates ----
        if (w >= 3) {
            f32x4 accX = mmk<8>(h0ex + (size_t)(s & 1) * 65536 + hoff, Bx);       // d0(s)
            f32x4 accH = mmk<8>(h1ex + (size_t)((s - 1) & 1) * 65536 + hoff, Bh); // d1(s-1)
            float* Gb = &G[1][0][0];
#pragma unroll
            for (int i = 0; i < 4; ++i) {
                int rc = ((l >> 4) * 4 + i) * 17 + (l & 15);
                if (j < 2) Gb[j * 272 + rc] = accX[i] + accH[i];
                else { Gb[2 * 272 + rc] = accX[i]; Gb[3 * 272 + rc] = accH[i]; }
            }
        }
        __syncthreads();
        if (w == 3)
            h_update(&G[1][0][0], H1M, h1ex + (size_t)(s & 1) * 65536 + slice_off, l, bR, bZ, bNi, bNh);
        barrier(++ticket);

        // ---- stage C: fc1 (even-cg blocks, wave 0) ----
        if (w == 0 && !(cg & 1)) {
            f32x4 acc = {0.f,0.f,0.f,0.f};
            const _Float16* ap = h1ex + (size_t)(s & 1) * 65536 + hoff;
#pragma unroll
            for (int kt = 0; kt < 8; ++kt)
                acc = __builtin_amdgcn_mfma_f32_16x16x32_f16(
                    *(const f16x8*)(ap + kt * 32),
                    *(const f16x8*)(FC1S + kt * 512 + l * 8), acc, 0, 0, 0);
#pragma unroll
            for (int i = 0; i < 4; ++i) {
                int row = (l >> 4) * 4 + i, col = l & 15;
                f1ex[(size_t)(g16 + row) * 128 + 16 * (cg >> 1) + col] =
                    (_Float16)fmaxf(acc[i] + f1breg, 0.f);
            }
        }
        barrier(++ticket);

        // ---- stage D: fc2 + output + pv feedback (cg 0, wave 0) ----
        if (w == 0 && cg == 0) {
            f32x4 acc = {0.f,0.f,0.f,0.f};
            const _Float16* ap = f1ex + (size_t)(g16 + (l & 15)) * 128 + (l >> 4) * 8;
#pragma unroll
            for (int kt = 0; kt < 4; ++kt)
                acc = __builtin_amdgcn_mfma_f32_16x16x32_f16(
                    *(const f16x8*)(ap + kt * 32),
                    *(const f16x8*)(FC2S + kt * 512 + l * 8), acc, 0, 0, 0);
#pragma unroll
            for (int i = 0; i < 4; ++i) {
                int row = (l >> 4) * 4 + i, col = l & 15;
                float y = acc[i] + f2breg;
                out[(size_t)(g16 + row) * 4096 + (size_t)s * 16 + col] = y;
                pvex[(g16 + row) * 16 + col] = (_Float16)y;
            }
        }
        barrier(++ticket);
    }
}

extern "C" void kernel_launch(void* const* d_in, const int* in_sizes, int n_in,
                              void* d_out, int out_size, void* d_ws, size_t ws_size,
                              hipStream_t stream)
{
    const float* x_cv    = (const float*)d_in[0];
    const float* x_tgt   = (const float*)d_in[1];
    const float* pv_init = (const float*)d_in[2];
    const int*   scen    = (const int*)d_in[3];
    const float* emb     = (const float*)d_in[4];
    const float* eWih0 = (const float*)d_in[5];
    const float* eWhh0 = (const float*)d_in[6];
    const float* ebih0 = (const float*)d_in[7];
    const float* ebhh0 = (const float*)d_in[8];
    const float* eWih1 = (const float*)d_in[9];
    const float* eWhh1 = (const float*)d_in[10];
    const float* ebih1 = (const float*)d_in[11];
    const float* ebhh1 = (const float*)d_in[12];
    const float* dWih0 = (const float*)d_in[13];
    const float* dWhh0 = (const float*)d_in[14];
    const float* dbih0 = (const float*)d_in[15];
    const float* dbhh0 = (const float*)d_in[16];
    const float* dWih1 = (const float*)d_in[17];
    const float* dWhh1 = (const float*)d_in[18];
    const float* dbih1 = (const float*)d_in[19];
    const float* dbhh1 = (const float*)d_in[20];
    const float* fc1W = (const float*)d_in[21];
    const float* fc1b = (const float*)d_in[22];
    const float* fc2W = (const float*)d_in[23];
    const float* fc2b = (const float*)d_in[24];
    float* out = (float*)d_out;

    _Float16* W = (_Float16*)d_ws;
    float* bias = (float*)((char*)d_ws + BIAS_BYTE_OFF);
    char* exch = (char*)d_ws + EXCH_BYTE_OFF;

    // zero flags + exchange (h0ex/h1ex zero-init doubles as h(-1)=0)
    hipMemsetAsync(exch, 0, EX_BYTES, stream);

    auto lp = [&](const float* src, unsigned off, int K_src, int KT, int GT) {
        int total = KT * GT * 64;
        prep_w<<<(total + 255) / 256, 256, 0, stream>>>(src, W + off, K_src, GT, total);
    };
    lp(eWih0, OFF_E0IH, 96, 3, 48);
    lp(eWhh0, OFF_E0HH, 256, 8, 48);
    lp(eWih1, OFF_E1IH, 256, 8, 48);
    lp(eWhh1, OFF_E1HH, 256, 8, 48);
    lp(dWih0, OFF_D0IH, 80, 3, 48);    // K 80 zero-padded to 96
    lp(dWhh0, OFF_D0HH, 256, 8, 48);
    lp(dWih1, OFF_D1IH, 256, 8, 48);
    lp(dWhh1, OFF_D1HH, 256, 8, 48);
    lp(fc1W, OFF_FC1, 256, 8, 8);
    lp(fc2W, OFF_FC2, 128, 4, 1);
    prep_bias<<<1, 256, 0, stream>>>(ebih0, ebhh0, bias);
    prep_bias<<<1, 256, 0, stream>>>(ebih1, ebhh1, bias + 1024);
    prep_bias<<<1, 256, 0, stream>>>(dbih0, dbhh0, bias + 2048);
    prep_bias<<<1, 256, 0, stream>>>(dbih1, dbhh1, bias + 3072);

    plant<<<256, 384, 0, stream>>>(x_cv, x_tgt, pv_init, scen, emb,
                                   W, bias, fc1b, fc2b, exch, out);
}

// Round 5
// 3525.645 us; speedup vs baseline: 7.2027x; 4.0902x over previous
//
#include <hip/hip_runtime.h>

// GRUPlant tensor-parallel persistent kernel, round 5 (round-4 syntax fix:
// VMEM asm modifier order is `off offset:N sc0 sc1`).
// 256 blocks x 384 threads; group g = blocks [16g,16g+16) shares 16 batch rows;
// block cg owns hidden cols [16cg,16cg+16). Gate weights live in VGPRs.
// Exchange via IC-coherent sc0/sc1 loads/stores (NO fences, L2 stays hot).
// Flags: one 128B line each, single-writer atomic store + load-only polling.
// Decoder: 2 barriers/step; fc1+fc2 fused into block cg==0 + pvflag.

typedef _Float16 f16x8 __attribute__((ext_vector_type(8)));
typedef float f32x4 __attribute__((ext_vector_type(4)));

#define XSTR 104   // 96 + 8 pad (f16)
#define HSTR 264   // 256 + 8 pad (f16)
#define YSTR 136   // 128 + 8 pad (f16)

// ---- pre-swizzled weight layout in d_ws (f16 elems; chunk = 512 f16 = 1KB) ----
#define OFF_E0IH 0u
#define OFF_E0HH 73728u
#define OFF_E1IH 270336u
#define OFF_E1HH 466944u
#define OFF_D0IH 663552u     // K=80 zero-padded to 96
#define OFF_D0HH 737280u
#define OFF_D1IH 933888u
#define OFF_D1HH 1130496u
#define OFF_FC1  1327104u    // 8kt x 8gt
#define OFF_FC2  1359872u    // 4kt x 1gt
#define W_TOTAL_F16 1361920u
#define BIAS_BYTE_OFF 2723840u
#define EXCH_BYTE_OFF 2740224u
// ---- exchange region (bytes, relative) ----
#define EX_H0 0          // [2][256][256] f16
#define EX_H1 262144     // [2][256][256] f16
#define EX_PV 524288     // [256][16] f16
#define EX_FLAGS 532480  // 16 groups x 17 flags x 128 B
#define EX_BYTES 567296

__device__ __forceinline__ float sigm(float x) { return 1.f / (1.f + __expf(-x)); }
__device__ __forceinline__ float tanh_fast(float x) { return 1.f - 2.f / (__expf(2.f * x) + 1.f); }

__device__ __forceinline__ f32x4 mfma(f16x8 a, f16x8 b, f32x4 c) {
    return __builtin_amdgcn_mfma_f32_16x16x32_f16(a, b, c, 0, 0, 0);
}

// ---- coherent (IC-level) memory helpers: bypass L1+L2 via sc0 sc1 ----
__device__ __forceinline__ void store_coh_f16(_Float16* p, _Float16 v) {
    union { _Float16 h; unsigned short u; } cv; cv.h = v;
    unsigned int ui = cv.u;
    asm volatile("global_store_short %0, %1, off sc0 sc1" :: "v"(p), "v"(ui) : "memory");
}
__device__ __forceinline__ unsigned short load_coh_u16(const _Float16* p) {
    unsigned int r;
    asm volatile("global_load_ushort %0, %1, off sc0 sc1\n\ts_waitcnt vmcnt(0)"
                 : "=v"(r) : "v"(p) : "memory");
    return (unsigned short)r;
}

// cooperative: stage one 16x256 f16 h-matrix (rows stride 256) into LDS (stride HSTR)
__device__ __forceinline__ void stage_h(const _Float16* src, _Float16* dst, int tid) {
    if (tid < 256) {
        int row = tid >> 4, c = tid & 15;
        const _Float16* p = src + (size_t)row * 256 + c * 16;
        f16x8 a, b;
        asm volatile(
            "global_load_dwordx4 %0, %2, off sc0 sc1\n\t"
            "global_load_dwordx4 %1, %2, off offset:16 sc0 sc1\n\t"
            "s_waitcnt vmcnt(0)"
            : "=v"(a), "=v"(b) : "v"(p) : "memory");
        *(f16x8*)(dst + row * HSTR + c * 16) = a;
        *(f16x8*)(dst + row * HSTR + c * 16 + 8) = b;
    }
}
// two matrices, one waitcnt
__device__ __forceinline__ void stage_h2(const _Float16* s0, const _Float16* s1,
                                         _Float16* d0, _Float16* d1, int tid) {
    if (tid < 256) {
        int row = tid >> 4, c = tid & 15;
        const _Float16* p0 = s0 + (size_t)row * 256 + c * 16;
        const _Float16* p1 = s1 + (size_t)row * 256 + c * 16;
        f16x8 a, b, e, f;
        asm volatile(
            "global_load_dwordx4 %0, %4, off sc0 sc1\n\t"
            "global_load_dwordx4 %1, %4, off offset:16 sc0 sc1\n\t"
            "global_load_dwordx4 %2, %5, off sc0 sc1\n\t"
            "global_load_dwordx4 %3, %5, off offset:16 sc0 sc1\n\t"
            "s_waitcnt vmcnt(0)"
            : "=v"(a), "=v"(b), "=v"(e), "=v"(f) : "v"(p0), "v"(p1) : "memory");
        *(f16x8*)(d0 + row * HSTR + c * 16) = a;
        *(f16x8*)(d0 + row * HSTR + c * 16 + 8) = b;
        *(f16x8*)(d1 + row * HSTR + c * 16) = e;
        *(f16x8*)(d1 + row * HSTR + c * 16 + 8) = f;
    }
}

// ---- prep: swizzle (rows x K_src) fp32 weight into MFMA-B fragment chunks ----
__global__ __launch_bounds__(256) void prep_w(const float* __restrict__ W,
                                              _Float16* __restrict__ dst,
                                              int K_src, int GT, int total_threads) {
    int idx = blockIdx.x * 256 + threadIdx.x;
    if (idx >= total_threads) return;
    int l = idx & 63, c = idx >> 6;
    int kt = c / GT, gt = c - kt * GT;
    int g = gt * 16 + (l & 15);
    int k0 = kt * 32 + (l >> 4) * 8;
    _Float16 tmp[8];
#pragma unroll
    for (int j = 0; j < 8; ++j) {
        int k = k0 + j;
        tmp[j] = (k < K_src) ? (_Float16)W[(size_t)g * K_src + k] : (_Float16)0.f;
    }
    *(f16x8*)(dst + (size_t)c * 512 + (size_t)l * 8) = *(f16x8*)tmp;
}

__global__ __launch_bounds__(256) void prep_bias(const float* __restrict__ bih,
                                                 const float* __restrict__ bhh,
                                                 float* __restrict__ dst) {
    int i = threadIdx.x;
    dst[i]       = bih[i]       + bhh[i];
    dst[256 + i] = bih[256 + i] + bhh[256 + i];
    dst[512 + i] = bih[512 + i];
    dst[768 + i] = bhh[512 + i];
}

template <int KT>
__device__ __forceinline__ f32x4 mmk(const _Float16* ap, const f16x8 (&B)[8]) {
    f32x4 acc = {0.f, 0.f, 0.f, 0.f};
#pragma unroll
    for (int kt = 0; kt < KT; ++kt)
        acc = mfma(*(const f16x8*)(ap + kt * 32), B[kt], acc);
    return acc;
}

__device__ __forceinline__ void h_update(const float* Gb, float* HM,
                                         _Float16* hex_slice, int l,
                                         float bR, float bZ, float bNi, float bNh) {
#pragma unroll
    for (int i = 0; i < 4; ++i) {
        int row = (l >> 4) * 4 + i, col = l & 15;
        int rc = row * 17 + col;
        float r = sigm(Gb[rc] + bR);
        float z = sigm(Gb[272 + rc] + bZ);
        float n = tanh_fast(Gb[2 * 272 + rc] + bNi + r * (Gb[3 * 272 + rc] + bNh));
        float hp = HM[row * 16 + col];
        float hn = (1.f - z) * n + z * hp;
        HM[row * 16 + col] = hn;
        store_coh_f16(hex_slice + (size_t)row * 256 + col, (_Float16)hn);
    }
}

__global__ __launch_bounds__(384, 2) void plant(
    const float* __restrict__ x_cv, const float* __restrict__ x_tgt,
    const float* __restrict__ pv_init, const int* __restrict__ scen,
    const float* __restrict__ emb,
    const _Float16* __restrict__ Wsw, const float* __restrict__ bias4,
    const float* __restrict__ fc1b, const float* __restrict__ fc2b,
    char* __restrict__ exch, float* __restrict__ out)
{
    __shared__ _Float16 XF[16 * XSTR];
    __shared__ _Float16 HA0[16 * HSTR];
    __shared__ _Float16 HA1[16 * HSTR];
    __shared__ _Float16 YF[16 * YSTR];
    __shared__ float G[2][4][272];
    __shared__ float H0M[256], H1M[256];

    const int tid = threadIdx.x;
    const int l = tid & 63, w = tid >> 6;
    const int g = blockIdx.x >> 4, cg = blockIdx.x & 15;
    const int g16 = g * 16;
    const int j = (w < 3) ? w : w - 3;      // gate role: 0=r,1=z,2=n
    const int gt = j * 16 + cg;

    _Float16* h0ex = (_Float16*)(exch + EX_H0);
    _Float16* h1ex = (_Float16*)(exch + EX_H1);
    _Float16* pvex = (_Float16*)(exch + EX_PV);
    int* gflags = (int*)(exch + EX_FLAGS) + g * (17 * 32);
    int* pvflag = gflags + 16 * 32;

    const int arow = l & 15, acol8 = (l >> 4) * 8;
    const size_t slice_off = (size_t)g16 * 256 + cg * 16;
    const _Float16* XFp = XF + arow * XSTR + acol8;
    const _Float16* HA0p = HA0 + arow * HSTR + acol8;
    const _Float16* HA1p = HA1 + arow * HSTR + acol8;

    int ticket = 0;
    auto barrier = [&](int target) {
        __syncthreads();   // drains vmcnt(0) per wave -> all coherent stores done
        if (w == 0) {
            if (l == 0)
                __hip_atomic_store(&gflags[cg * 32], target, __ATOMIC_RELAXED,
                                   __HIP_MEMORY_SCOPE_AGENT);
            if (l < 16)
                while (__hip_atomic_load(&gflags[l * 32], __ATOMIC_RELAXED,
                                         __HIP_MEMORY_SCOPE_AGENT) < target)
                    __builtin_amdgcn_s_sleep(1);
        }
        __syncthreads();
    };

    // ---- init ----
    for (int i = tid; i < 256; i += 384) { H0M[i] = 0.f; H1M[i] = 0.f; }
    if (tid < 256) {                        // scenario embedding -> XF[64..95]
        int row = tid >> 4, c2 = (tid & 15) * 2;
        int sc = scen[g16 + row];
        XF[row * XSTR + 64 + c2]     = (_Float16)emb[sc * 32 + c2];
        XF[row * XSTR + 64 + c2 + 1] = (_Float16)emb[sc * 32 + c2 + 1];
    }

    // encoder gate weights -> registers
    f16x8 Bx[8], Bh[8];
    {
        unsigned offi = (w < 3) ? OFF_E0IH : OFF_E1IH;
        unsigned offh = (w < 3) ? OFF_E0HH : OFF_E1HH;
        int ktx = (w < 3) ? 3 : 8;
#pragma unroll
        for (int kt = 0; kt < 8; ++kt) {
            if (kt < ktx) Bx[kt] = *(const f16x8*)(Wsw + offi + (size_t)(kt * 48 + gt) * 512 + l * 8);
            Bh[kt] = *(const f16x8*)(Wsw + offh + (size_t)(kt * 48 + gt) * 512 + l * 8);
        }
    }
    float bR = 0.f, bZ = 0.f, bNi = 0.f, bNh = 0.f;
    {
        const float* bb = (w == 0) ? bias4 : bias4 + 1024;
        int hc = cg * 16 + (l & 15);
        if (w == 0 || w == 3) { bR = bb[hc]; bZ = bb[256 + hc]; bNi = bb[512 + hc]; bNh = bb[768 + hc]; }
    }

    float4 xpre;
    const float* xsrc0 = x_cv + (size_t)(g16 + (tid >> 4)) * (512 * 64) + (tid & 15) * 4;
    if (tid < 256) xpre = *(const float4*)xsrc0;
    __syncthreads();

    // ================= encoder: t = 0..512 (layer1 lags by 1) =================
    for (int t = 0; t <= 512; ++t) {
        if (t < 512 && tid < 256) {
            int row = tid >> 4, c4 = (tid & 15) * 4;
            XF[row * XSTR + c4]     = (_Float16)xpre.x;
            XF[row * XSTR + c4 + 1] = (_Float16)xpre.y;
            XF[row * XSTR + c4 + 2] = (_Float16)xpre.z;
            XF[row * XSTR + c4 + 3] = (_Float16)xpre.w;
        }
        stage_h2(h0ex + (size_t)((t - 1) & 1) * 65536 + (size_t)g16 * 256,
                 h1ex + (size_t)(t & 1) * 65536 + (size_t)g16 * 256, HA0, HA1, tid);
        __syncthreads();
        if (tid < 256 && t + 1 < 512) xpre = *(const float4*)(xsrc0 + (size_t)(t + 1) * 64);

        bool doL0 = (w < 3) && (t < 512);
        bool doL1 = (w >= 3) && (t > 0);
        if (doL0 || doL1) {
            f32x4 accX, accH;
            if (doL0) { accX = mmk<3>(XFp, Bx);  accH = mmk<8>(HA0p, Bh); }
            else      { accX = mmk<8>(HA0p, Bx); accH = mmk<8>(HA1p, Bh); }
            float* Gb = &G[(w < 3) ? 0 : 1][0][0];
#pragma unroll
            for (int i = 0; i < 4; ++i) {
                int rc = ((l >> 4) * 4 + i) * 17 + (l & 15);
                if (j < 2) Gb[j * 272 + rc] = accX[i] + accH[i];
                else { Gb[2 * 272 + rc] = accX[i]; Gb[3 * 272 + rc] = accH[i]; }
            }
        }
        __syncthreads();
        if (w == 0 && t < 512)
            h_update(&G[0][0][0], H0M, h0ex + (size_t)(t & 1) * 65536 + slice_off, l, bR, bZ, bNi, bNh);
        if (w == 3 && t > 0)
            h_update(&G[1][0][0], H1M, h1ex + (size_t)((t - 1) & 1) * 65536 + slice_off, l, bR, bZ, bNi, bNh);
        barrier(++ticket);
    }

    // ================= phase switch: decoder weights =================
    {
        unsigned offi = (w < 3) ? OFF_D0IH : OFF_D1IH;
        unsigned offh = (w < 3) ? OFF_D0HH : OFF_D1HH;
        int ktx = (w < 3) ? 3 : 8;
#pragma unroll
        for (int kt = 0; kt < 8; ++kt) {
            if (kt < ktx) Bx[kt] = *(const f16x8*)(Wsw + offi + (size_t)(kt * 48 + gt) * 512 + l * 8);
            Bh[kt] = *(const f16x8*)(Wsw + offh + (size_t)(kt * 48 + gt) * 512 + l * 8);
        }
        const float* bb = (w == 0) ? bias4 + 2048 : bias4 + 3072;
        int hc = cg * 16 + (l & 15);
        if (w == 0 || w == 3) { bR = bb[hc]; bZ = bb[256 + hc]; bNi = bb[512 + hc]; bNh = bb[768 + hc]; }
    }
    // fc weights -> registers (used by cg==0 only; loaded by all to stay uniform)
    f16x8 Bf1a[8], Bf1b[8], Bf2[4];
#pragma unroll
    for (int kt = 0; kt < 8; ++kt) {
        Bf1a[kt] = *(const f16x8*)(Wsw + OFF_FC1 + (size_t)(kt * 8 + w) * 512 + l * 8);
        Bf1b[kt] = (w < 2) ? *(const f16x8*)(Wsw + OFF_FC1 + (size_t)(kt * 8 + w + 6) * 512 + l * 8)
                           : Bf1a[kt];
    }
#pragma unroll
    for (int kt = 0; kt < 4; ++kt)
        Bf2[kt] = *(const f16x8*)(Wsw + OFF_FC2 + (size_t)kt * 512 + l * 8);
    float f1b0 = fc1b[w * 16 + (l & 15)];
    float f1b1 = (w < 2) ? fc1b[(w + 6) * 16 + (l & 15)] : 0.f;
    float f2breg = fc2b[l & 15];

    const float* xsrc1 = x_tgt + (size_t)(g16 + (tid >> 4)) * (256 * 64) + (tid & 15) * 4;
    if (tid < 256) xpre = *(const float4*)xsrc1;
    __syncthreads();

    // ================= decoder: s = 0..255, 2 barriers + 1 pv-wait per step ====
    for (int s = 0; s < 256; ++s) {
        if (tid < 256) {
            int row = tid >> 4, c4 = (tid & 15) * 4;
            XF[row * XSTR + c4]     = (_Float16)xpre.x;
            XF[row * XSTR + c4 + 1] = (_Float16)xpre.y;
            XF[row * XSTR + c4 + 2] = (_Float16)xpre.z;
            XF[row * XSTR + c4 + 3] = (_Float16)xpre.w;
        }
        if (s > 0 && w == 0 && l == 0)
            while (__hip_atomic_load(pvflag, __ATOMIC_RELAXED, __HIP_MEMORY_SCOPE_AGENT) < s)
                __builtin_amdgcn_s_sleep(1);
        __syncthreads();
        if (tid < 256) {
            int row = tid >> 4, col = tid & 15;
            if (s == 0) {
                XF[row * XSTR + 64 + col] = (_Float16)pv_init[(g16 + row) * 16 + col];
            } else {
                union { unsigned short u; _Float16 h; } cv;
                cv.u = load_coh_u16(pvex + (size_t)(g16 + row) * 16 + col);
                XF[row * XSTR + 64 + col] = cv.h;
            }
        }
        stage_h(h0ex + (size_t)((s - 1) & 1) * 65536 + (size_t)g16 * 256, HA0, tid);
        __syncthreads();
        if (tid < 256 && s + 1 < 256) xpre = *(const float4*)(xsrc1 + (size_t)(s + 1) * 64);

        // ---- stage A: d0 ----
        if (w < 3) {
            f32x4 accX = mmk<3>(XFp, Bx);
            f32x4 accH = mmk<8>(HA0p, Bh);
            float* Gb = &G[0][0][0];
#pragma unroll
            for (int i = 0; i < 4; ++i) {
                int rc = ((l >> 4) * 4 + i) * 17 + (l & 15);
                if (j < 2) Gb[j * 272 + rc] = accX[i] + accH[i];
                else { Gb[2 * 272 + rc] = accX[i]; Gb[3 * 272 + rc] = accH[i]; }
            }
        }
        __syncthreads();
        if (w == 0)
            h_update(&G[0][0][0], H0M, h0ex + (size_t)(s & 1) * 65536 + slice_off, l, bR, bZ, bNi, bNh);
        barrier(++ticket);

        // ---- stage B: d1 ----
        stage_h2(h0ex + (size_t)(s & 1) * 65536 + (size_t)g16 * 256,
                 h1ex + (size_t)((s - 1) & 1) * 65536 + (size_t)g16 * 256, HA0, HA1, tid);
        __syncthreads();
        if (w >= 3) {
            f32x4 accX = mmk<8>(HA0p, Bx);
            f32x4 accH = mmk<8>(HA1p, Bh);
            float* Gb = &G[1][0][0];
#pragma unroll
            for (int i = 0; i < 4; ++i) {
                int rc = ((l >> 4) * 4 + i) * 17 + (l & 15);
                if (j < 2) Gb[j * 272 + rc] = accX[i] + accH[i];
                else { Gb[2 * 272 + rc] = accX[i]; Gb[3 * 272 + rc] = accH[i]; }
            }
        }
        __syncthreads();
        if (w == 3)
            h_update(&G[1][0][0], H1M, h1ex + (size_t)(s & 1) * 65536 + slice_off, l, bR, bZ, bNi, bNh);
        barrier(++ticket);

        // ---- fc head: block cg==0 only ----
        if (cg == 0) {
            stage_h(h1ex + (size_t)(s & 1) * 65536 + (size_t)g16 * 256, HA1, tid);
            __syncthreads();
            {
                f32x4 a0 = {0.f,0.f,0.f,0.f}, a1 = a0;
                const _Float16* Ap = HA1 + (l & 15) * HSTR + ((l >> 4) * 8);
#pragma unroll
                for (int kt = 0; kt < 8; ++kt) {
                    f16x8 a = *(const f16x8*)(Ap + kt * 32);
                    a0 = mfma(a, Bf1a[kt], a0);
                    a1 = mfma(a, Bf1b[kt], a1);
                }
#pragma unroll
                for (int i = 0; i < 4; ++i) {
                    int row = (l >> 4) * 4 + i, col = l & 15;
                    YF[row * YSTR + w * 16 + col] = (_Float16)fmaxf(a0[i] + f1b0, 0.f);
                    if (w < 2)
                        YF[row * YSTR + (w + 6) * 16 + col] = (_Float16)fmaxf(a1[i] + f1b1, 0.f);
                }
            }
            __syncthreads();
            if (w == 0) {
                f32x4 acc = {0.f,0.f,0.f,0.f};
                const _Float16* Yp = YF + (l & 15) * YSTR + ((l >> 4) * 8);
#pragma unroll
                for (int kt = 0; kt < 4; ++kt)
                    acc = mfma(*(const f16x8*)(Yp + kt * 32), Bf2[kt], acc);
#pragma unroll
                for (int i = 0; i < 4; ++i) {
                    int row = (l >> 4) * 4 + i, col = l & 15;
                    float y = acc[i] + f2breg;
                    out[(size_t)(g16 + row) * 4096 + (size_t)s * 16 + col] = y;
                    store_coh_f16(pvex + (size_t)(g16 + row) * 16 + col, (_Float16)y);
                }
                asm volatile("s_waitcnt vmcnt(0)" ::: "memory");
                if (l == 0)
                    __hip_atomic_store(pvflag, s + 1, __ATOMIC_RELAXED, __HIP_MEMORY_SCOPE_AGENT);
            }
        }
    }
}

extern "C" void kernel_launch(void* const* d_in, const int* in_sizes, int n_in,
                              void* d_out, int out_size, void* d_ws, size_t ws_size,
                              hipStream_t stream)
{
    const float* x_cv    = (const float*)d_in[0];
    const float* x_tgt   = (const float*)d_in[1];
    const float* pv_init = (const float*)d_in[2];
    const int*   scen    = (const int*)d_in[3];
    const float* emb     = (const float*)d_in[4];
    const float* eWih0 = (const float*)d_in[5];
    const float* eWhh0 = (const float*)d_in[6];
    const float* ebih0 = (const float*)d_in[7];
    const float* ebhh0 = (const float*)d_in[8];
    const float* eWih1 = (const float*)d_in[9];
    const float* eWhh1 = (const float*)d_in[10];
    const float* ebih1 = (const float*)d_in[11];
    const float* ebhh1 = (const float*)d_in[12];
    const float* dWih0 = (const float*)d_in[13];
    const float* dWhh0 = (const float*)d_in[14];
    const float* dbih0 = (const float*)d_in[15];
    const float* dbhh0 = (const float*)d_in[16];
    const float* dWih1 = (const float*)d_in[17];
    const float* dWhh1 = (const float*)d_in[18];
    const float* dbih1 = (const float*)d_in[19];
    const float* dbhh1 = (const float*)d_in[20];
    const float* fc1W = (const float*)d_in[21];
    const float* fc1b = (const float*)d_in[22];
    const float* fc2W = (const float*)d_in[23];
    const float* fc2b = (const float*)d_in[24];
    float* out = (float*)d_out;

    _Float16* W = (_Float16*)d_ws;
    float* bias = (float*)((char*)d_ws + BIAS_BYTE_OFF);
    char* exch = (char*)d_ws + EXCH_BYTE_OFF;

    // zero flags + exchange (h0ex/h1ex zero-init doubles as h(-1)=0)
    hipMemsetAsync(exch, 0, EX_BYTES, stream);

    auto lp = [&](const float* src, unsigned off, int K_src, int KT, int GT) {
        int total = KT * GT * 64;
        prep_w<<<(total + 255) / 256, 256, 0, stream>>>(src, W + off, K_src, GT, total);
    };
    lp(eWih0, OFF_E0IH, 96, 3, 48);
    lp(eWhh0, OFF_E0HH, 256, 8, 48);
    lp(eWih1, OFF_E1IH, 256, 8, 48);
    lp(eWhh1, OFF_E1HH, 256, 8, 48);
    lp(dWih0, OFF_D0IH, 80, 3, 48);    // K 80 zero-padded to 96
    lp(dWhh0, OFF_D0HH, 256, 8, 48);
    lp(dWih1, OFF_D1IH, 256, 8, 48);
    lp(dWhh1, OFF_D1HH, 256, 8, 48);
    lp(fc1W, OFF_FC1, 256, 8, 8);
    lp(fc2W, OFF_FC2, 128, 4, 1);
    prep_bias<<<1, 256, 0, stream>>>(ebih0, ebhh0, bias);
    prep_bias<<<1, 256, 0, stream>>>(ebih1, ebhh1, bias + 1024);
    prep_bias<<<1, 256, 0, stream>>>(dbih0, dbhh0, bias + 2048);
    prep_bias<<<1, 256, 0, stream>>>(dbih1, dbhh1, bias + 3072);

    plant<<<256, 384, 0, stream>>>(x_cv, x_tgt, pv_init, scen, emb,
                                   W, bias, fc1b, fc2b, exch, out);
}